// Round 7
// baseline (168.418 us; speedup 1.0000x reference)
//
#include <hip/hip_runtime.h>

#define BATCH 16
#define NINST 8              // instance labels 1..8; 0 = background
#define NPB   (720 * 1280)   // elements per batch = 921600
#define NV4   (NPB / 4)      // float4 items per batch = 230400
#define MARGIN_VAR  0.5f
#define MARGIN_DIST 3.0f

// ws layout (floats): [0..127] cnt[b][l], [128..255] sum[b][l], [256..383] psum[b][l]

__global__ __launch_bounds__(256) void k_stats(const float4* __restrict__ x,
                                               const int4* __restrict__ g,
                                               float* __restrict__ ws) {
    const int b = blockIdx.y;
    const float4* xb = x + (size_t)b * NV4;
    const int4*   gb = g + (size_t)b * NV4;

    float s[NINST], c[NINST];
#pragma unroll
    for (int l = 0; l < NINST; ++l) { s[l] = 0.f; c[l] = 0.f; }

    const int stride = gridDim.x * blockDim.x;
    for (int i = blockIdx.x * blockDim.x + threadIdx.x; i < NV4; i += stride) {
        float4 xv = xb[i];
        int4   gv = gb[i];
#pragma unroll
        for (int l = 1; l <= NINST; ++l) {
            bool m0 = (gv.x == l), m1 = (gv.y == l), m2 = (gv.z == l), m3 = (gv.w == l);
            s[l - 1] += (m0 ? xv.x : 0.f) + (m1 ? xv.y : 0.f)
                      + (m2 ? xv.z : 0.f) + (m3 ? xv.w : 0.f);
            c[l - 1] += (m0 ? 1.f : 0.f) + (m1 ? 1.f : 0.f)
                      + (m2 ? 1.f : 0.f) + (m3 ? 1.f : 0.f);
        }
    }

    // wave64 reduce each accumulator
#pragma unroll
    for (int l = 0; l < NINST; ++l) {
#pragma unroll
        for (int off = 32; off; off >>= 1) {
            s[l] += __shfl_down(s[l], off);
            c[l] += __shfl_down(c[l], off);
        }
    }

    __shared__ float red[4][2 * NINST];
    const int lane = threadIdx.x & 63, wid = threadIdx.x >> 6;
    if (lane == 0) {
#pragma unroll
        for (int l = 0; l < NINST; ++l) {
            red[wid][l]         = c[l];
            red[wid][NINST + l] = s[l];
        }
    }
    __syncthreads();
    if (threadIdx.x < 2 * NINST) {
        float v = red[0][threadIdx.x] + red[1][threadIdx.x] +
                  red[2][threadIdx.x] + red[3][threadIdx.x];
        int l     = threadIdx.x & (NINST - 1);
        int isSum = threadIdx.x >> 3;   // 0 -> cnt, 1 -> sum
        atomicAdd(&ws[isSum * 128 + b * NINST + l], v);
    }
}

__global__ __launch_bounds__(256) void k_pull(const float4* __restrict__ x,
                                              const int4* __restrict__ g,
                                              float* __restrict__ ws) {
    const int b = blockIdx.y;
    const float4* xb = x + (size_t)b * NV4;
    const int4*   gb = g + (size_t)b * NV4;

    __shared__ float smu[NINST + 1];
    if (threadIdx.x == 0) smu[0] = 0.f;
    if (threadIdx.x < NINST) {
        float cnt = ws[b * NINST + threadIdx.x];
        float sum = ws[128 + b * NINST + threadIdx.x];
        smu[1 + threadIdx.x] = sum / fmaxf(cnt, 1.f);
    }
    __syncthreads();

    float p[NINST];
#pragma unroll
    for (int l = 0; l < NINST; ++l) p[l] = 0.f;

    const int stride = gridDim.x * blockDim.x;
    for (int i = blockIdx.x * blockDim.x + threadIdx.x; i < NV4; i += stride) {
        float4 xv = xb[i];
        int4   gv = gb[i];
        float xa0 = xv.x, xa1 = xv.y, xa2 = xv.z, xa3 = xv.w;
        int g0 = ((unsigned)gv.x <= NINST) ? gv.x : 0;
        int g1 = ((unsigned)gv.y <= NINST) ? gv.y : 0;
        int g2 = ((unsigned)gv.z <= NINST) ? gv.z : 0;
        int g3 = ((unsigned)gv.w <= NINST) ? gv.w : 0;
        float t0 = fmaxf(fabsf(xa0 - smu[g0]) - MARGIN_VAR, 0.f);
        float t1 = fmaxf(fabsf(xa1 - smu[g1]) - MARGIN_VAR, 0.f);
        float t2 = fmaxf(fabsf(xa2 - smu[g2]) - MARGIN_VAR, 0.f);
        float t3 = fmaxf(fabsf(xa3 - smu[g3]) - MARGIN_VAR, 0.f);
        float p0 = t0 * t0, p1 = t1 * t1, p2 = t2 * t2, p3 = t3 * t3;
#pragma unroll
        for (int l = 1; l <= NINST; ++l) {
            p[l - 1] += ((g0 == l) ? p0 : 0.f) + ((g1 == l) ? p1 : 0.f)
                      + ((g2 == l) ? p2 : 0.f) + ((g3 == l) ? p3 : 0.f);
        }
    }

#pragma unroll
    for (int l = 0; l < NINST; ++l) {
#pragma unroll
        for (int off = 32; off; off >>= 1)
            p[l] += __shfl_down(p[l], off);
    }

    __shared__ float red[4][NINST];
    const int lane = threadIdx.x & 63, wid = threadIdx.x >> 6;
    if (lane == 0) {
#pragma unroll
        for (int l = 0; l < NINST; ++l) red[wid][l] = p[l];
    }
    __syncthreads();
    if (threadIdx.x < NINST) {
        float v = red[0][threadIdx.x] + red[1][threadIdx.x] +
                  red[2][threadIdx.x] + red[3][threadIdx.x];
        atomicAdd(&ws[256 + b * NINST + threadIdx.x], v);
    }
}

__global__ __launch_bounds__(128) void k_final(const float* __restrict__ ws,
                                               float* __restrict__ out) {
    const int tid = threadIdx.x;        // 0..127 = b*8 + l
    const int b = tid >> 3;

    float cnt = ws[tid];
    float sum = ws[128 + tid];
    float ps  = ws[256 + tid];
    float valid  = (cnt > 0.f) ? 1.f : 0.f;
    float mean   = sum / fmaxf(cnt, 1.f);
    float pull_i = ps / fmaxf(cnt, 1.f);

    __shared__ float smean[128];
    __shared__ float svalid[128];
    smean[tid]  = mean;
    svalid[tid] = valid;
    __syncthreads();

    float ploss = 0.f, npush = 0.f;
#pragma unroll
    for (int j = 0; j < NINST; ++j) {
        if (j == (tid & 7)) continue;
        float pv = valid * svalid[b * NINST + j];
        float d  = fabsf(mean - smean[b * NINST + j]);
        float t  = fmaxf(2.f * MARGIN_DIST - d, 0.f);
        ploss += pv * t * t;
        npush += pv;
    }

    float vals[4] = {pull_i * valid, valid, ploss, npush};
#pragma unroll
    for (int k = 0; k < 4; ++k) {
#pragma unroll
        for (int off = 32; off; off >>= 1)
            vals[k] += __shfl_down(vals[k], off);
    }

    __shared__ float r2[2][4];
    const int lane = tid & 63, wid = tid >> 6;
    if (lane == 0) {
#pragma unroll
        for (int k = 0; k < 4; ++k) r2[wid][k] = vals[k];
    }
    __syncthreads();
    if (tid == 0) {
        float pulls = r2[0][0] + r2[1][0];
        float npl   = r2[0][1] + r2[1][1];
        float pls   = r2[0][2] + r2[1][2];
        float nps   = r2[0][3] + r2[1][3];
        float pull_loss = (npl > 0.f) ? pulls / fmaxf(npl, 1.f) : 0.f;
        float push_loss = (nps > 0.f) ? pls / fmaxf(nps, 1.f) : 0.f;
        out[0] = push_loss + pull_loss;
    }
}

extern "C" void kernel_launch(void* const* d_in, const int* in_sizes, int n_in,
                              void* d_out, int out_size, void* d_ws, size_t ws_size,
                              hipStream_t stream) {
    const float* x = (const float*)d_in[0];
    const int*   g = (const int*)d_in[1];
    float* out = (float*)d_out;
    float* ws  = (float*)d_ws;

    hipMemsetAsync(d_ws, 0, 384 * sizeof(float), stream);

    dim3 grid(128, BATCH);
    k_stats<<<grid, 256, 0, stream>>>((const float4*)x, (const int4*)g, ws);
    k_pull<<<grid, 256, 0, stream>>>((const float4*)x, (const int4*)g, ws);
    k_final<<<1, 128, 0, stream>>>(ws, out);
}

// Round 8
// 164.945 us; speedup vs baseline: 1.0211x; 1.0211x over previous
//
#include <hip/hip_runtime.h>

#define BATCH 16
#define NINST 8              // instance labels 1..8; 0 = background
#define NPB   (720 * 1280)   // elements per batch = 921600
#define NV4   (NPB / 4)      // float4 items per batch = 230400
#define BLKX  225            // 225 blocks * 1024 float4 = NV4 exactly
#define MARGIN_VAR  0.5f
#define MARGIN_DIST 3.0f

// ws layout (floats): [0..127] cnt[b][l], [128..255] sum[b][l], [256..383] psum[b][l]

__device__ __forceinline__ void acc_stats(float4 xv, int4 gv,
                                          float (&s)[NINST], float (&c)[NINST]) {
#pragma unroll
    for (int l = 1; l <= NINST; ++l) {
        bool m0 = (gv.x == l), m1 = (gv.y == l), m2 = (gv.z == l), m3 = (gv.w == l);
        s[l - 1] += (m0 ? xv.x : 0.f) + (m1 ? xv.y : 0.f)
                  + (m2 ? xv.z : 0.f) + (m3 ? xv.w : 0.f);
        c[l - 1] += (m0 ? 1.f : 0.f) + (m1 ? 1.f : 0.f)
                  + (m2 ? 1.f : 0.f) + (m3 ? 1.f : 0.f);
    }
}

__global__ __launch_bounds__(256) void k_stats(const float4* __restrict__ x,
                                               const int4* __restrict__ g,
                                               float* __restrict__ ws) {
    const int b = blockIdx.y;
    const size_t base = (size_t)b * NV4 + (size_t)blockIdx.x * 1024 + threadIdx.x;

    // issue all 8 independent loads up front (128 B MLP per thread)
    float4 xv0 = x[base];
    float4 xv1 = x[base + 256];
    float4 xv2 = x[base + 512];
    float4 xv3 = x[base + 768];
    int4   gv0 = g[base];
    int4   gv1 = g[base + 256];
    int4   gv2 = g[base + 512];
    int4   gv3 = g[base + 768];

    float s[NINST], c[NINST];
#pragma unroll
    for (int l = 0; l < NINST; ++l) { s[l] = 0.f; c[l] = 0.f; }

    acc_stats(xv0, gv0, s, c);
    acc_stats(xv1, gv1, s, c);
    acc_stats(xv2, gv2, s, c);
    acc_stats(xv3, gv3, s, c);

    // wave64 reduce each accumulator
#pragma unroll
    for (int l = 0; l < NINST; ++l) {
#pragma unroll
        for (int off = 32; off; off >>= 1) {
            s[l] += __shfl_down(s[l], off);
            c[l] += __shfl_down(c[l], off);
        }
    }

    __shared__ float red[4][2 * NINST];
    const int lane = threadIdx.x & 63, wid = threadIdx.x >> 6;
    if (lane == 0) {
#pragma unroll
        for (int l = 0; l < NINST; ++l) {
            red[wid][l]         = c[l];
            red[wid][NINST + l] = s[l];
        }
    }
    __syncthreads();
    if (threadIdx.x < 2 * NINST) {
        float v = red[0][threadIdx.x] + red[1][threadIdx.x] +
                  red[2][threadIdx.x] + red[3][threadIdx.x];
        int l     = threadIdx.x & (NINST - 1);
        int isSum = threadIdx.x >> 3;   // 0 -> cnt, 1 -> sum
        atomicAdd(&ws[isSum * 128 + b * NINST + l], v);
    }
}

__device__ __forceinline__ void acc_pull(float4 xv, int4 gv,
                                         const float* __restrict__ smu,
                                         float (&p)[NINST]) {
    int g0 = ((unsigned)gv.x <= NINST) ? gv.x : 0;
    int g1 = ((unsigned)gv.y <= NINST) ? gv.y : 0;
    int g2 = ((unsigned)gv.z <= NINST) ? gv.z : 0;
    int g3 = ((unsigned)gv.w <= NINST) ? gv.w : 0;
    float t0 = fmaxf(fabsf(xv.x - smu[g0]) - MARGIN_VAR, 0.f);
    float t1 = fmaxf(fabsf(xv.y - smu[g1]) - MARGIN_VAR, 0.f);
    float t2 = fmaxf(fabsf(xv.z - smu[g2]) - MARGIN_VAR, 0.f);
    float t3 = fmaxf(fabsf(xv.w - smu[g3]) - MARGIN_VAR, 0.f);
    float p0 = t0 * t0, p1 = t1 * t1, p2 = t2 * t2, p3 = t3 * t3;
#pragma unroll
    for (int l = 1; l <= NINST; ++l) {
        p[l - 1] += ((g0 == l) ? p0 : 0.f) + ((g1 == l) ? p1 : 0.f)
                  + ((g2 == l) ? p2 : 0.f) + ((g3 == l) ? p3 : 0.f);
    }
}

__global__ __launch_bounds__(256) void k_pull(const float4* __restrict__ x,
                                              const int4* __restrict__ g,
                                              float* __restrict__ ws) {
    const int b = blockIdx.y;
    const size_t base = (size_t)b * NV4 + (size_t)blockIdx.x * 1024 + threadIdx.x;

    float4 xv0 = x[base];
    float4 xv1 = x[base + 256];
    float4 xv2 = x[base + 512];
    float4 xv3 = x[base + 768];
    int4   gv0 = g[base];
    int4   gv1 = g[base + 256];
    int4   gv2 = g[base + 512];
    int4   gv3 = g[base + 768];

    __shared__ float smu[NINST + 1];
    if (threadIdx.x == 0) smu[0] = 0.f;
    if (threadIdx.x < NINST) {
        float cnt = ws[b * NINST + threadIdx.x];
        float sum = ws[128 + b * NINST + threadIdx.x];
        smu[1 + threadIdx.x] = sum / fmaxf(cnt, 1.f);
    }
    __syncthreads();

    float p[NINST];
#pragma unroll
    for (int l = 0; l < NINST; ++l) p[l] = 0.f;

    acc_pull(xv0, gv0, smu, p);
    acc_pull(xv1, gv1, smu, p);
    acc_pull(xv2, gv2, smu, p);
    acc_pull(xv3, gv3, smu, p);

#pragma unroll
    for (int l = 0; l < NINST; ++l) {
#pragma unroll
        for (int off = 32; off; off >>= 1)
            p[l] += __shfl_down(p[l], off);
    }

    __shared__ float red[4][NINST];
    const int lane = threadIdx.x & 63, wid = threadIdx.x >> 6;
    if (lane == 0) {
#pragma unroll
        for (int l = 0; l < NINST; ++l) red[wid][l] = p[l];
    }
    __syncthreads();
    if (threadIdx.x < NINST) {
        float v = red[0][threadIdx.x] + red[1][threadIdx.x] +
                  red[2][threadIdx.x] + red[3][threadIdx.x];
        atomicAdd(&ws[256 + b * NINST + threadIdx.x], v);
    }
}

__global__ __launch_bounds__(128) void k_final(const float* __restrict__ ws,
                                               float* __restrict__ out) {
    const int tid = threadIdx.x;        // 0..127 = b*8 + l
    const int b = tid >> 3;

    float cnt = ws[tid];
    float sum = ws[128 + tid];
    float ps  = ws[256 + tid];
    float valid  = (cnt > 0.f) ? 1.f : 0.f;
    float mean   = sum / fmaxf(cnt, 1.f);
    float pull_i = ps / fmaxf(cnt, 1.f);

    __shared__ float smean[128];
    __shared__ float svalid[128];
    smean[tid]  = mean;
    svalid[tid] = valid;
    __syncthreads();

    float ploss = 0.f, npush = 0.f;
#pragma unroll
    for (int j = 0; j < NINST; ++j) {
        if (j == (tid & 7)) continue;
        float pv = valid * svalid[b * NINST + j];
        float d  = fabsf(mean - smean[b * NINST + j]);
        float t  = fmaxf(2.f * MARGIN_DIST - d, 0.f);
        ploss += pv * t * t;
        npush += pv;
    }

    float vals[4] = {pull_i * valid, valid, ploss, npush};
#pragma unroll
    for (int k = 0; k < 4; ++k) {
#pragma unroll
        for (int off = 32; off; off >>= 1)
            vals[k] += __shfl_down(vals[k], off);
    }

    __shared__ float r2[2][4];
    const int lane = tid & 63, wid = tid >> 6;
    if (lane == 0) {
#pragma unroll
        for (int k = 0; k < 4; ++k) r2[wid][k] = vals[k];
    }
    __syncthreads();
    if (tid == 0) {
        float pulls = r2[0][0] + r2[1][0];
        float npl   = r2[0][1] + r2[1][1];
        float pls   = r2[0][2] + r2[1][2];
        float nps   = r2[0][3] + r2[1][3];
        float pull_loss = (npl > 0.f) ? pulls / fmaxf(npl, 1.f) : 0.f;
        float push_loss = (nps > 0.f) ? pls / fmaxf(nps, 1.f) : 0.f;
        out[0] = push_loss + pull_loss;
    }
}

extern "C" void kernel_launch(void* const* d_in, const int* in_sizes, int n_in,
                              void* d_out, int out_size, void* d_ws, size_t ws_size,
                              hipStream_t stream) {
    const float* x = (const float*)d_in[0];
    const int*   g = (const int*)d_in[1];
    float* out = (float*)d_out;
    float* ws  = (float*)d_ws;

    hipMemsetAsync(d_ws, 0, 384 * sizeof(float), stream);

    dim3 grid(BLKX, BATCH);
    k_stats<<<grid, 256, 0, stream>>>((const float4*)x, (const int4*)g, ws);
    k_pull<<<grid, 256, 0, stream>>>((const float4*)x, (const int4*)g, ws);
    k_final<<<1, 128, 0, stream>>>(ws, out);
}